// Round 10
// baseline (1525.972 us; speedup 1.0000x reference)
//
#include <hip/hip_runtime.h>

// LSTM: L=2, B=32, T=256, N=M=1024, gates 4M=4096
// R10 = R9 with the compile artifact removed (design unchanged):
// R8 + (1) x/seq(t+1) PREFETCH: loads issued right after the h tile lands
// (poll already licensed them), fly under h-GEMM+reduce+epilogue+store; tail
// only lands them into bufX and runs the x-GEMM. 2nd 64KB LDS buffer; gred
// aliases bufX (lifetimes separated by S4/S5). Wave 0 issues its share after
// its exchange-store drain (keeps drain vmcnt(0) store-only).
// (2) one-sided layer coupling: l0 polls own 64 flags, l1 polls all 128.

typedef __bf16 bf16x8 __attribute__((ext_vector_type(8)));
typedef float  f32x4  __attribute__((ext_vector_type(4)));
typedef unsigned u32x4 __attribute__((ext_vector_type(4)));

__device__ __forceinline__ unsigned short f2bf(float f) {
    union { float f; unsigned u; } v; v.f = f;
    unsigned u = v.u;
    unsigned r = u + 0x7fffu + ((u >> 16) & 1u);   // RNE
    return (unsigned short)(r >> 16);
}
__device__ __forceinline__ float sigmoidf_fast(float x) {
    return 1.0f / (1.0f + __expf(-x));
}
__device__ __forceinline__ float tanhf_fast(float x) {
    return 1.0f - 2.0f / (__expf(2.0f * x) + 1.0f);
}

// src: (L*4096, 1024) f32 -> dst: (L*4096, 2048) bf16 at column offset `off`
__global__ void cvt_w_concat(const float* __restrict__ src,
                             unsigned short* __restrict__ dst, int off, int n4) {
    int i = blockIdx.x * blockDim.x + threadIdx.x;
    int stride = gridDim.x * blockDim.x;
    for (; i < n4; i += stride) {
        float4 v = ((const float4*)src)[i];
        ushort4 o;
        o.x = f2bf(v.x); o.y = f2bf(v.y); o.z = f2bf(v.z); o.w = f2bf(v.w);
        int row = i >> 8;
        int c4  = i & 255;
        *(ushort4*)&dst[(size_t)row * 2048 + off + c4 * 4] = o;
    }
}

// x (B,T,N) f32 -> per-t tiles [t][blk 64][b 32][mi 16] bf16; one block per t
__global__ void cvt_x_tiles(const float* __restrict__ x,
                            unsigned short* __restrict__ xT) {
    int t = blockIdx.x, tid = threadIdx.x;
    unsigned short* tile = xT + (size_t)t * 32768;
    for (int b = 0; b < 32; ++b) {
        float4 v = *(const float4*)&x[((size_t)b * 256 + t) * 1024 + tid * 4];
        ushort4 o;
        o.x = f2bf(v.x); o.y = f2bf(v.y); o.z = f2bf(v.z); o.w = f2bf(v.w);
        *(ushort4*)&tile[(tid >> 2) * 512 + b * 16 + (tid & 3) * 4] = o;
    }
}

// h0 (L,B,M) f32 -> tiles [l][blk][b][mi] bf16; one block per l
__global__ void cvt_h0_tiles(const float* __restrict__ h0,
                             unsigned short* __restrict__ h0T) {
    int l = blockIdx.x, tid = threadIdx.x;
    unsigned short* tile = h0T + (size_t)l * 32768;
    for (int b = 0; b < 32; ++b) {
        float4 v = *(const float4*)&h0[((size_t)l * 32 + b) * 1024 + tid * 4];
        ushort4 o;
        o.x = f2bf(v.x); o.y = f2bf(v.y); o.z = f2bf(v.z); o.w = f2bf(v.w);
        *(ushort4*)&tile[(tid >> 2) * 512 + b * 16 + (tid & 3) * 4] = o;
    }
}

// outT [t][blk][b][mi] f32 -> out (B,T,M) f32; one block per t
__global__ void out_transpose(const float* __restrict__ outT,
                              float* __restrict__ out) {
    int t = blockIdx.x, tid = threadIdx.x;
    const float* tile = outT + (size_t)t * 32768;
    for (int b = 0; b < 32; ++b) {
        float4 v = *(const float4*)&tile[(tid >> 2) * 512 + b * 16 + (tid & 3) * 4];
        *(float4*)&out[((size_t)b * 256 + t) * 1024 + tid * 4] = v;
    }
}

__device__ __forceinline__ void pollge(const unsigned* fp, unsigned tgt) {
    while (true) {
        unsigned v = __hip_atomic_load(fp, __ATOMIC_RELAXED,
                                       __HIP_MEMORY_SCOPE_AGENT);
        if (__all((int)(v >= tgt))) break;
        __builtin_amdgcn_s_sleep(1);
    }
}

__global__ __launch_bounds__(256, 1) void lstm_fused(
    const unsigned short* __restrict__ Wcat,  // (L,4096,2048) bf16 [Wih|Whh]
    const unsigned short* __restrict__ xT,    // 256 x 64KB tiles bf16
    unsigned short* __restrict__ seqT,        // 256 x 64KB tiles (layer0 h)
    const unsigned short* __restrict__ h0T,   // 2 x 64KB tiles
    unsigned short* __restrict__ hparT,       // 2 x 64KB tiles (layer1 parity)
    float* __restrict__ outT,                 // 256 x 128KB f32 tiles
    const float* __restrict__ c0,             // (L,32,1024) f32
    const float* __restrict__ bih, const float* __restrict__ bhh,
    float* __restrict__ out, unsigned int* flags)   // flags: [2][64] u32 packed
{
    __shared__ __align__(16) unsigned short bufH[32][1024];  // 64KB h tile
    __shared__ __align__(16) unsigned short bufX[32][1024];  // 64KB x (gred alias)
    __shared__ __align__(16) unsigned short hout_bf[32][16]; // 1KB
    __shared__ __align__(16) float hout_f[32][16];           // 2KB

    const int tid  = threadIdx.x;
    const int lane = tid & 63;
    const int w    = tid >> 6;
    const int l    = blockIdx.x >> 6;
    const int bidl = blockIdx.x & 63;
    const int m0   = bidl * 16;
    const int n    = lane & 15;
    const int g    = lane >> 4;
    const int lk   = g * 8;
    const int nn7  = n & 7;

    char* const bH = (char*)&bufH[0][0];
    char* const bX = (char*)&bufX[0][0];
    // gred aliases bufX (40960B <= 64KB). Lifetimes: gred written in act(s)
    // [after S5(s-1), which orders past tail's bufX x-gemm reads], read before
    // S4(s); bufX x-data landed in tail(s) [after S4], read before S5(s+..).
    float (*gred)[2][4][16][20] = (float (*)[2][4][16][20])bX;

    // ---- persistent weights: wave w owns K-window [w*256,+256) in each half
    bf16x8 wx[32], wh[32];
    const unsigned short* Wl = Wcat + (size_t)l * 4096 * 2048;
    #pragma unroll
    for (int ct = 0; ct < 4; ct++) {
        int vc = ct * 16 + n;
        size_t jrow = (size_t)((vc & 3) * 1024 + m0 + (vc >> 2));
        #pragma unroll
        for (int kc = 0; kc < 8; kc++) {
            wx[ct*8+kc] = *(const bf16x8*)&Wl[jrow*2048 +        w*256 + kc*32 + lk];
            wh[ct*8+kc] = *(const bf16x8*)&Wl[jrow*2048 + 1024 + w*256 + kc*32 + lk];
        }
    }

    // ---- epilogue ownership: thread -> (batch eb, m-pair em,em+1)
    const int eb = lane >> 1;
    const int q  = lane & 1;
    const int em = m0 + 4 * w + 2 * q;
    float bs0[4], bs1[4];
    #pragma unroll
    for (int gg = 0; gg < 4; gg++) {
        bs0[gg] = bih[l*4096 + gg*1024 + em]     + bhh[l*4096 + gg*1024 + em];
        bs1[gg] = bih[l*4096 + gg*1024 + em + 1] + bhh[l*4096 + gg*1024 + em + 1];
    }
    float2 creg = *(const float2*)&c0[(size_t)l * 32768 + eb * 1024 + em];
    float2 hlast = {0.f, 0.f};
    const int uh = eb >> 4, urow = eb & 15;

    // ---- wave-local staging: chunk si -> blk=w*16+si; lane -> (sb, halfk)
    const int sb     = lane >> 1;
    const int halfk  = lane & 1;
    const int srcOff = w * 16384 + sb * 32 + halfk * 16;
    const int sbRow  = sb * 2048;
    const int ldsCol = w * 512 + halfk * 16;
    const int swz    = (sb & 7) << 4;

    // ---- frag reads: phys = r*2048 + ((w*512+kc*64+g*16) ^ ((r&7)<<4))
    const int hb64 = (nn7 >> 2) * 64;
    const int gx16 = (g ^ (nn7 & 3)) * 16;
    const int rOffA0 = n * 2048 + w * 512 + gx16 + hb64;        // even kc
    const int rOffA1 = n * 2048 + w * 512 + gx16 + (64 - hb64); // odd  kc

    f32x4 acc0[4] = {}, acc1[4] = {};
    u32x4 hv[16];

    auto issue = [&](const char* tb, bool byp) {
        const char* gp = tb + srcOff;
        if (byp) {
            #pragma unroll
            for (int si = 0; si < 16; si++)
                asm volatile("global_load_dwordx4 %0, %1, off sc0 sc1"
                             : "=v"(hv[si]) : "v"(gp + si * 1024) : "memory");
        } else {
            #pragma unroll
            for (int si = 0; si < 16; si++)
                asm volatile("global_load_dwordx4 %0, %1, off"
                             : "=v"(hv[si]) : "v"(gp + si * 1024) : "memory");
        }
    };

    auto gemmbuf = [&](const char* base, const bf16x8* wfv) {
        const char* pA0 = base + rOffA0;
        const char* pA1 = base + rOffA1;
        const char* pB0 = pA0 + 16 * 2048;
        const char* pB1 = pA1 + 16 * 2048;
        #pragma unroll
        for (int kc2 = 0; kc2 < 4; kc2++) {
            bf16x8 a0 = *(const bf16x8*)(pA0 + kc2 * 128);
            bf16x8 a1 = *(const bf16x8*)(pB0 + kc2 * 128);
            #pragma unroll
            for (int ct = 0; ct < 4; ct++) {
                acc0[ct] = __builtin_amdgcn_mfma_f32_16x16x32_bf16(a0, wfv[ct*8+2*kc2],   acc0[ct],0,0,0);
                acc1[ct] = __builtin_amdgcn_mfma_f32_16x16x32_bf16(a1, wfv[ct*8+2*kc2],   acc1[ct],0,0,0);
            }
            bf16x8 b0 = *(const bf16x8*)(pA1 + kc2 * 128);
            bf16x8 b1 = *(const bf16x8*)(pB1 + kc2 * 128);
            #pragma unroll
            for (int ct = 0; ct < 4; ct++) {
                acc0[ct] = __builtin_amdgcn_mfma_f32_16x16x32_bf16(b0, wfv[ct*8+2*kc2+1], acc0[ct],0,0,0);
                acc1[ct] = __builtin_amdgcn_mfma_f32_16x16x32_bf16(b1, wfv[ct*8+2*kc2+1], acc1[ct],0,0,0);
            }
        }
    };

    // h stage+gemm with counted-vmcnt interleave (R8-proven), dst = bufH
    auto stage_gemm_h = [&](const char* tb) {
        const char* gp = tb + srcOff;
        #pragma unroll
        for (int si = 0; si < 16; si++)
            asm volatile("global_load_dwordx4 %0, %1, off sc0 sc1"
                         : "=v"(hv[si]) : "v"(gp + si * 1024) : "memory");
        const char* pA0 = bH + rOffA0;
        const char* pA1 = bH + rOffA1;
        const char* pB0 = pA0 + 16 * 2048;
        const char* pB1 = pA1 + 16 * 2048;
#define SGRP(G4, VM) \
        asm volatile("s_waitcnt vmcnt(" VM ")" ::: "memory"); \
        _Pragma("unroll") \
        for (int si = 4*(G4); si < 4*(G4)+4; si++) \
            *(u32x4*)(bH + sbRow + ((ldsCol + si*32) ^ swz)) = hv[si]; \
        { \
            bf16x8 a0 = *(const bf16x8*)(pA0 + (G4)*128); \
            bf16x8 a1 = *(const bf16x8*)(pB0 + (G4)*128); \
            _Pragma("unroll") \
            for (int ct = 0; ct < 4; ct++) { \
                acc0[ct] = __builtin_amdgcn_mfma_f32_16x16x32_bf16(a0, wh[ct*8+2*(G4)],   acc0[ct],0,0,0); \
                acc1[ct] = __builtin_amdgcn_mfma_f32_16x16x32_bf16(a1, wh[ct*8+2*(G4)],   acc1[ct],0,0,0); \
            } \
            bf16x8 b0 = *(const bf16x8*)(pA1 + (G4)*128); \
            bf16x8 b1 = *(const bf16x8*)(pB1 + (G4)*128); \
            _Pragma("unroll") \
            for (int ct = 0; ct < 4; ct++) { \
                acc0[ct] = __builtin_amdgcn_mfma_f32_16x16x32_bf16(b0, wh[ct*8+2*(G4)+1], acc0[ct],0,0,0); \
                acc1[ct] = __builtin_amdgcn_mfma_f32_16x16x32_bf16(b1, wh[ct*8+2*(G4)+1], acc1[ct],0,0,0); \
            } \
        }
        SGRP(0, "12") SGRP(1, "8") SGRP(2, "4") SGRP(3, "0")
#undef SGRP
    };

    // ---- prologue: layer-0 computes x(0) partials into acc (via bufX)
    if (l == 0) {
        issue((const char*)xT, false);
        asm volatile("s_waitcnt vmcnt(0)" ::: "memory");
        #pragma unroll
        for (int si = 0; si < 16; si++)
            *(u32x4*)(bX + sbRow + ((ldsCol + si * 32) ^ swz)) = hv[si];
        gemmbuf(bX, wx);
    }
    __syncthreads();   // all bufX prologue reads done before first gred write

    const int lag = l * 2;
    #pragma unroll 1
    for (int s = 0; s < 258; s++) {
        const int  t    = s - lag;
        const bool act  = (t >= 0) && (t < 256);
        const int  tn   = t + 1;
        const bool xact = (tn >= ((l == 0) ? 1 : 0)) && (tn <= 255);
        const char* xsrc = (l == 0) ? (const char*)(xT   + (size_t)tn * 32768)
                                    : (const char*)(seqT + (size_t)tn * 32768);

        if (act) {
            // h(t-1): published <= iter s-1, confirmed by last poll
            const char* hb = (t == 0)
                ? (const char*)(h0T + (size_t)l * 32768)
                : (l == 0 ? (const char*)(seqT + (size_t)(t - 1) * 32768)
                          : (const char*)(hparT + (size_t)((t - 1) & 1) * 32768));
            stage_gemm_h(hb);             // acc += h-partials (x already in)

            // ---- PREFETCH x/seq(t+1): licensed by last poll (flags >= s =>
            // seq(s-1)=seq(t+1) published for l=1). Wave 0 defers past drain.
            if (xact && w != 0) issue(xsrc, l == 1);

            // ---- K-partials -> gred (bufX alias; past x-reads ordered by S5)
            {
                int r0 = g * 4;
                #pragma unroll
                for (int ct = 0; ct < 4; ct++) {
                    *(f32x4*)&gred[w][0][ct][n][r0] = acc0[ct];
                    *(f32x4*)&gred[w][1][ct][n][r0] = acc1[ct];
                }
            }
            __syncthreads();                                  // S3
            float g8[8];
            #pragma unroll
            for (int j = 0; j < 8; j++) {
                g8[j] = (gred[0][uh][w][8*q+j][urow] + gred[1][uh][w][8*q+j][urow])
                      + (gred[2][uh][w][8*q+j][urow] + gred[3][uh][w][8*q+j][urow]);
            }
            float gi0 = g8[0] + bs0[0], gf0 = g8[1] + bs0[1];
            float gg0 = g8[2] + bs0[2], go0 = g8[3] + bs0[3];
            float gi1 = g8[4] + bs1[0], gf1 = g8[5] + bs1[1];
            float gg1 = g8[6] + bs1[2], go1 = g8[7] + bs1[3];

            float c0n = sigmoidf_fast(gf0) * creg.x + sigmoidf_fast(gi0) * tanhf_fast(gg0);
            float c1n = sigmoidf_fast(gf1) * creg.y + sigmoidf_fast(gi1) * tanhf_fast(gg1);
            float h0v = sigmoidf_fast(go0) * tanhf_fast(c0n);
            float h1v = sigmoidf_fast(go1) * tanhf_fast(c1n);
            creg.x = c0n; creg.y = c1n;
            hlast.x = h0v; hlast.y = h1v;

            unsigned hp = (unsigned)f2bf(h0v) | ((unsigned)f2bf(h1v) << 16);
            *(unsigned*)&hout_bf[eb][4*w + 2*q] = hp;
            if (l == 1) {
                float2 hv2 = {h0v, h1v};
                *(float2*)&hout_f[eb][4*w + 2*q] = hv2;
            }
            __syncthreads();                                  // S4
            // ---- exchange store + drain + flag (wave 0, no x-loads pending)
            if (tid < 64) {
                u32x4 v = *(const u32x4*)((const char*)&hout_bf[0][0] + tid * 16);
                const char* dp = (l == 0)
                    ? (const char*)(seqT  + (size_t)t * 32768)       + bidl * 1024 + tid * 16
                    : (const char*)(hparT + (size_t)(t & 1) * 32768) + bidl * 1024 + tid * 16;
                asm volatile("global_store_dwordx4 %0, %1, off sc0 sc1"
                             :: "v"(dp), "v"(v) : "memory");
                asm volatile("s_waitcnt vmcnt(0)" ::: "memory");
                if (tid == 0)
                    __hip_atomic_store(flags + l * 64 + bidl, (unsigned)(s + 1),
                                       __ATOMIC_RELAXED, __HIP_MEMORY_SCOPE_AGENT);
            } else if (l == 1 && tid < 192) {
                int u = tid - 64;
                f32x4 v = *(const f32x4*)((const char*)&hout_f[0][0] + u * 16);
                *(f32x4*)((char*)outT + (size_t)t * 131072 + bidl * 2048 + u * 16) = v;
            }
            if (xact && w == 0) issue(xsrc, l == 1);   // wave 0 post-drain
        } else {
            if (tid == 0)
                __hip_atomic_store(flags + l * 64 + bidl, (unsigned)(s + 1),
                                   __ATOMIC_RELAXED, __HIP_MEMORY_SCOPE_AGENT);
            if (xact) issue(xsrc, l == 1);             // l1 s=1: seq(0)
        }

        // ---- tail: land prefetched tile into bufX, x-gemm for t+1
        if (xact) {
            asm volatile("s_waitcnt vmcnt(0)" ::: "memory");
            #pragma unroll
            for (int si = 0; si < 16; si++)
                *(u32x4*)(bX + sbRow + ((ldsCol + si * 32) ^ swz)) = hv[si];
            #pragma unroll
            for (int ct = 0; ct < 4; ct++) {
                acc0[ct] = (f32x4){0.f, 0.f, 0.f, 0.f};
                acc1[ct] = (f32x4){0.f, 0.f, 0.f, 0.f};
            }
            gemmbuf(bX, wx);
        }

        // ---- one-sided coupling: l0 polls own layer; l1 polls both
        if (tid < (l ? 128 : 64)) pollge(flags + tid, (unsigned)(s + 1));
        __syncthreads();                                      // S5
    }

    // ---- final states
    float* hF = out + (size_t)8192 * 1024 + (size_t)l * 32768;
    float* cF = out + (size_t)8192 * 1024 + 65536 + (size_t)l * 32768;
    float2 hf2 = {hlast.x, hlast.y};
    *(float2*)&hF[eb * 1024 + em] = hf2;
    float2 cf2 = {creg.x, creg.y};
    *(float2*)&cF[eb * 1024 + em] = cf2;
}

extern "C" void kernel_launch(void* const* d_in, const int* in_sizes, int n_in,
                              void* d_out, int out_size, void* d_ws, size_t ws_size,
                              hipStream_t stream)
{
    const float* x   = (const float*)d_in[0];
    const float* h0  = (const float*)d_in[1];
    const float* c0  = (const float*)d_in[2];
    const float* Wih = (const float*)d_in[3];
    const float* Whh = (const float*)d_in[4];
    const float* bih = (const float*)d_in[5];
    const float* bhh = (const float*)d_in[6];
    float* out = (float*)d_out;

    char* p = (char*)d_ws;
    unsigned short* xT    = (unsigned short*)p; p += (size_t)256 * 32768 * 2;      // 16 MB
    unsigned short* seqT  = (unsigned short*)p; p += (size_t)256 * 32768 * 2;      // 16 MB
    unsigned short* Wcat  = (unsigned short*)p; p += (size_t)2 * 4096 * 2048 * 2;  // 32 MB
    unsigned short* h0T   = (unsigned short*)p; p += (size_t)2 * 32768 * 2;        // 128 KB
    unsigned short* hparT = (unsigned short*)p; p += (size_t)2 * 32768 * 2;        // 128 KB
    float*          outT  = (float*)p;          p += (size_t)256 * 32768 * 4;      // 32 MB
    unsigned int*   flags = (unsigned int*)p;   p += 4096;

    hipMemsetAsync(flags, 0, 4096, stream);
    cvt_w_concat<<<1024, 256, 0, stream>>>(Wih, Wcat, 0,    2 * 4096 * 256);
    cvt_w_concat<<<1024, 256, 0, stream>>>(Whh, Wcat, 1024, 2 * 4096 * 256);
    cvt_x_tiles<<<256, 256, 0, stream>>>(x, xT);
    cvt_h0_tiles<<<2, 256, 0, stream>>>(h0, h0T);

    lstm_fused<<<128, 256, 0, stream>>>(Wcat, xT, seqT, h0T, hparT, outT,
                                        c0, bih, bhh, out, flags);

    out_transpose<<<256, 256, 0, stream>>>(outT, out);
}

// Round 11
// 1334.906 us; speedup vs baseline: 1.1431x; 1.1431x over previous
//
#include <hip/hip_runtime.h>

// LSTM: L=2, B=32, T=256, N=M=1024, gates 4M=4096
// R11 = R8 + correctly-ordered overlap of store-drain and x-prefetch:
//  (1) per-thread DIRECT exchange stores (no hout LDS bounce): every thread
//      stores its own 4B of h (l1: +8B outT), then all 4 waves drain vmcnt(0)
//      in PARALLEL before S4; flag after S4 is free. Removes wave-0's serial
//      post-S4 chain (LDS read + 1KB store + lone drain).
//  (2) x/seq(t+1) prefetch issued right after stage_gemm_h (licensed by the
//      previous poll); loads land DURING the store drain (store RT dominates),
//      so the tail's counted landing groups are ~no-ops. No wave-0 special
//      case (FIFO vmcnt lesson from R10).
//  (3) symmetric all-128 poll (one-sided reverted; isolate the change).

typedef __bf16 bf16x8 __attribute__((ext_vector_type(8)));
typedef float  f32x4  __attribute__((ext_vector_type(4)));
typedef unsigned u32x4 __attribute__((ext_vector_type(4)));

__device__ __forceinline__ unsigned short f2bf(float f) {
    union { float f; unsigned u; } v; v.f = f;
    unsigned u = v.u;
    unsigned r = u + 0x7fffu + ((u >> 16) & 1u);   // RNE
    return (unsigned short)(r >> 16);
}
__device__ __forceinline__ float sigmoidf_fast(float x) {
    return 1.0f / (1.0f + __expf(-x));
}
__device__ __forceinline__ float tanhf_fast(float x) {
    return 1.0f - 2.0f / (__expf(2.0f * x) + 1.0f);
}

// src: (L*4096, 1024) f32 -> dst: (L*4096, 2048) bf16 at column offset `off`
__global__ void cvt_w_concat(const float* __restrict__ src,
                             unsigned short* __restrict__ dst, int off, int n4) {
    int i = blockIdx.x * blockDim.x + threadIdx.x;
    int stride = gridDim.x * blockDim.x;
    for (; i < n4; i += stride) {
        float4 v = ((const float4*)src)[i];
        ushort4 o;
        o.x = f2bf(v.x); o.y = f2bf(v.y); o.z = f2bf(v.z); o.w = f2bf(v.w);
        int row = i >> 8;
        int c4  = i & 255;
        *(ushort4*)&dst[(size_t)row * 2048 + off + c4 * 4] = o;
    }
}

// x (B,T,N) f32 -> per-t tiles [t][blk 64][b 32][mi 16] bf16; one block per t
__global__ void cvt_x_tiles(const float* __restrict__ x,
                            unsigned short* __restrict__ xT) {
    int t = blockIdx.x, tid = threadIdx.x;
    unsigned short* tile = xT + (size_t)t * 32768;
    for (int b = 0; b < 32; ++b) {
        float4 v = *(const float4*)&x[((size_t)b * 256 + t) * 1024 + tid * 4];
        ushort4 o;
        o.x = f2bf(v.x); o.y = f2bf(v.y); o.z = f2bf(v.z); o.w = f2bf(v.w);
        *(ushort4*)&tile[(tid >> 2) * 512 + b * 16 + (tid & 3) * 4] = o;
    }
}

// h0 (L,B,M) f32 -> tiles [l][blk][b][mi] bf16; one block per l
__global__ void cvt_h0_tiles(const float* __restrict__ h0,
                             unsigned short* __restrict__ h0T) {
    int l = blockIdx.x, tid = threadIdx.x;
    unsigned short* tile = h0T + (size_t)l * 32768;
    for (int b = 0; b < 32; ++b) {
        float4 v = *(const float4*)&h0[((size_t)l * 32 + b) * 1024 + tid * 4];
        ushort4 o;
        o.x = f2bf(v.x); o.y = f2bf(v.y); o.z = f2bf(v.z); o.w = f2bf(v.w);
        *(ushort4*)&tile[(tid >> 2) * 512 + b * 16 + (tid & 3) * 4] = o;
    }
}

// outT [t][blk][b][mi] f32 -> out (B,T,M) f32; one block per t
__global__ void out_transpose(const float* __restrict__ outT,
                              float* __restrict__ out) {
    int t = blockIdx.x, tid = threadIdx.x;
    const float* tile = outT + (size_t)t * 32768;
    for (int b = 0; b < 32; ++b) {
        float4 v = *(const float4*)&tile[(tid >> 2) * 512 + b * 16 + (tid & 3) * 4];
        *(float4*)&out[((size_t)b * 256 + t) * 1024 + tid * 4] = v;
    }
}

__device__ __forceinline__ void pollge(const unsigned* fp, unsigned tgt) {
    while (true) {
        unsigned v = __hip_atomic_load(fp, __ATOMIC_RELAXED,
                                       __HIP_MEMORY_SCOPE_AGENT);
        if (__all((int)(v >= tgt))) break;
        __builtin_amdgcn_s_sleep(1);
    }
}

__global__ __launch_bounds__(256, 1) void lstm_fused(
    const unsigned short* __restrict__ Wcat,  // (L,4096,2048) bf16 [Wih|Whh]
    const unsigned short* __restrict__ xT,    // 256 x 64KB tiles bf16
    unsigned short* __restrict__ seqT,        // 256 x 64KB tiles (layer0 h)
    const unsigned short* __restrict__ h0T,   // 2 x 64KB tiles
    unsigned short* __restrict__ hparT,       // 2 x 64KB tiles (layer1 parity)
    float* __restrict__ outT,                 // 256 x 128KB f32 tiles
    const float* __restrict__ c0,             // (L,32,1024) f32
    const float* __restrict__ bih, const float* __restrict__ bhh,
    float* __restrict__ out, unsigned int* flags)   // flags: [2][64] u32 packed
{
    __shared__ __align__(16) unsigned short bufH[32][1024];  // 64KB h tile
    __shared__ __align__(16) unsigned short bufX[32][1024];  // 64KB x (gred alias)

    const int tid  = threadIdx.x;
    const int lane = tid & 63;
    const int w    = tid >> 6;
    const int l    = blockIdx.x >> 6;
    const int bidl = blockIdx.x & 63;
    const int m0   = bidl * 16;
    const int n    = lane & 15;
    const int g    = lane >> 4;
    const int lk   = g * 8;
    const int nn7  = n & 7;

    char* const bH = (char*)&bufH[0][0];
    char* const bX = (char*)&bufX[0][0];
    // gred aliases bufX (40960B <= 64KB). Lifetimes: bufX x-gemm reads happen
    // in tail(s-1) before S5(s-1); gred written in act(s) after S5, read in
    // reduce before S4(s); bufX x-landing in tail(s) happens after S4.
    float (*gred)[2][4][16][20] = (float (*)[2][4][16][20])bX;

    // ---- persistent weights: wave w owns K-window [w*256,+256) in each half
    bf16x8 wx[32], wh[32];
    const unsigned short* Wl = Wcat + (size_t)l * 4096 * 2048;
    #pragma unroll
    for (int ct = 0; ct < 4; ct++) {
        int vc = ct * 16 + n;
        size_t jrow = (size_t)((vc & 3) * 1024 + m0 + (vc >> 2));
        #pragma unroll
        for (int kc = 0; kc < 8; kc++) {
            wx[ct*8+kc] = *(const bf16x8*)&Wl[jrow*2048 +        w*256 + kc*32 + lk];
            wh[ct*8+kc] = *(const bf16x8*)&Wl[jrow*2048 + 1024 + w*256 + kc*32 + lk];
        }
    }

    // ---- epilogue ownership: thread -> (batch eb, m-pair em,em+1)
    const int eb = lane >> 1;
    const int q  = lane & 1;
    const int em = m0 + 4 * w + 2 * q;
    float bs0[4], bs1[4];
    #pragma unroll
    for (int gg = 0; gg < 4; gg++) {
        bs0[gg] = bih[l*4096 + gg*1024 + em]     + bhh[l*4096 + gg*1024 + em];
        bs1[gg] = bih[l*4096 + gg*1024 + em + 1] + bhh[l*4096 + gg*1024 + em + 1];
    }
    float2 creg = *(const float2*)&c0[(size_t)l * 32768 + eb * 1024 + em];
    float2 hlast = {0.f, 0.f};
    const int uh = eb >> 4, urow = eb & 15;

    // ---- direct exchange-store offset: thread -> tile byte eb*32 + m-pair
    const int exOff = bidl * 1024 + eb * 32 + (4 * w + 2 * q) * 2;
    const int outOff = bidl * 2048 + eb * 64 + (4 * w + 2 * q) * 4;

    // ---- wave-local staging: chunk si -> blk=w*16+si; lane -> (sb, halfk)
    const int sb     = lane >> 1;
    const int halfk  = lane & 1;
    const int srcOff = w * 16384 + sb * 32 + halfk * 16;
    const int sbRow  = sb * 2048;
    const int ldsCol = w * 512 + halfk * 16;
    const int swz    = (sb & 7) << 4;

    // ---- frag reads: phys = r*2048 + ((w*512+kc*64+g*16) ^ ((r&7)<<4))
    const int hb64 = (nn7 >> 2) * 64;
    const int gx16 = (g ^ (nn7 & 3)) * 16;
    const int rOffA0 = n * 2048 + w * 512 + gx16 + hb64;        // even kc
    const int rOffA1 = n * 2048 + w * 512 + gx16 + (64 - hb64); // odd  kc

    f32x4 acc0[4] = {}, acc1[4] = {};
    u32x4 hv[16];

    auto issue = [&](const char* tb, bool byp) {
        const char* gp = tb + srcOff;
        if (byp) {
            #pragma unroll
            for (int si = 0; si < 16; si++)
                asm volatile("global_load_dwordx4 %0, %1, off sc0 sc1"
                             : "=v"(hv[si]) : "v"(gp + si * 1024) : "memory");
        } else {
            #pragma unroll
            for (int si = 0; si < 16; si++)
                asm volatile("global_load_dwordx4 %0, %1, off"
                             : "=v"(hv[si]) : "v"(gp + si * 1024) : "memory");
        }
    };

    // h stage+gemm with counted-vmcnt interleave (R8-proven), dst = bufH
    auto stage_gemm_h = [&](const char* tb) {
        const char* gp = tb + srcOff;
        #pragma unroll
        for (int si = 0; si < 16; si++)
            asm volatile("global_load_dwordx4 %0, %1, off sc0 sc1"
                         : "=v"(hv[si]) : "v"(gp + si * 1024) : "memory");
        const char* pA0 = bH + rOffA0;
        const char* pA1 = bH + rOffA1;
        const char* pB0 = pA0 + 16 * 2048;
        const char* pB1 = pA1 + 16 * 2048;
#define SGRP(G4, VM) \
        asm volatile("s_waitcnt vmcnt(" VM ")" ::: "memory"); \
        _Pragma("unroll") \
        for (int si = 4*(G4); si < 4*(G4)+4; si++) \
            *(u32x4*)(bH + sbRow + ((ldsCol + si*32) ^ swz)) = hv[si]; \
        { \
            bf16x8 a0 = *(const bf16x8*)(pA0 + (G4)*128); \
            bf16x8 a1 = *(const bf16x8*)(pB0 + (G4)*128); \
            _Pragma("unroll") \
            for (int ct = 0; ct < 4; ct++) { \
                acc0[ct] = __builtin_amdgcn_mfma_f32_16x16x32_bf16(a0, wh[ct*8+2*(G4)],   acc0[ct],0,0,0); \
                acc1[ct] = __builtin_amdgcn_mfma_f32_16x16x32_bf16(a1, wh[ct*8+2*(G4)],   acc1[ct],0,0,0); \
            } \
            bf16x8 b0 = *(const bf16x8*)(pA1 + (G4)*128); \
            bf16x8 b1 = *(const bf16x8*)(pB1 + (G4)*128); \
            _Pragma("unroll") \
            for (int ct = 0; ct < 4; ct++) { \
                acc0[ct] = __builtin_amdgcn_mfma_f32_16x16x32_bf16(b0, wh[ct*8+2*(G4)+1], acc0[ct],0,0,0); \
                acc1[ct] = __builtin_amdgcn_mfma_f32_16x16x32_bf16(b1, wh[ct*8+2*(G4)+1], acc1[ct],0,0,0); \
            } \
        }
        SGRP(0, "12") SGRP(1, "8") SGRP(2, "4") SGRP(3, "0")
#undef SGRP
    };

    // ---- prologue: layer-0 computes x(0) partials into acc (via bufX)
    if (l == 0) {
        issue((const char*)xT, false);
        asm volatile("s_waitcnt vmcnt(0)" ::: "memory");
        #pragma unroll
        for (int si = 0; si < 16; si++)
            *(u32x4*)(bX + sbRow + ((ldsCol + si * 32) ^ swz)) = hv[si];
        const char* pA0 = bX + rOffA0;
        const char* pA1 = bX + rOffA1;
        const char* pB0 = pA0 + 16 * 2048;
        const char* pB1 = pA1 + 16 * 2048;
        #pragma unroll
        for (int kc2 = 0; kc2 < 4; kc2++) {
            bf16x8 a0 = *(const bf16x8*)(pA0 + kc2 * 128);
            bf16x8 a1 = *(const bf16x8*)(pB0 + kc2 * 128);
            #pragma unroll
            for (int ct = 0; ct < 4; ct++) {
                acc0[ct] = __builtin_amdgcn_mfma_f32_16x16x32_bf16(a0, wx[ct*8+2*kc2],   acc0[ct],0,0,0);
                acc1[ct] = __builtin_amdgcn_mfma_f32_16x16x32_bf16(a1, wx[ct*8+2*kc2],   acc1[ct],0,0,0);
            }
            bf16x8 b0 = *(const bf16x8*)(pA1 + kc2 * 128);
            bf16x8 b1 = *(const bf16x8*)(pB1 + kc2 * 128);
            #pragma unroll
            for (int ct = 0; ct < 4; ct++) {
                acc0[ct] = __builtin_amdgcn_mfma_f32_16x16x32_bf16(b0, wx[ct*8+2*kc2+1], acc0[ct],0,0,0);
                acc1[ct] = __builtin_amdgcn_mfma_f32_16x16x32_bf16(b1, wx[ct*8+2*kc2+1], acc1[ct],0,0,0);
            }
        }
    }
    __syncthreads();   // all bufX prologue reads done before first gred write

    const int lag = l * 2;
    #pragma unroll 1
    for (int s = 0; s < 258; s++) {
        const int  t    = s - lag;
        const bool act  = (t >= 0) && (t < 256);
        const int  tn   = t + 1;
        const bool xact = (tn >= ((l == 0) ? 1 : 0)) && (tn <= 255);
        const char* xsrc = (l == 0) ? (const char*)(xT   + (size_t)tn * 32768)
                                    : (const char*)(seqT + (size_t)tn * 32768);

        if (act) {
            // h(t-1): published <= iter s-1, confirmed by last poll
            const char* hb = (t == 0)
                ? (const char*)(h0T + (size_t)l * 32768)
                : (l == 0 ? (const char*)(seqT + (size_t)(t - 1) * 32768)
                          : (const char*)(hparT + (size_t)((t - 1) & 1) * 32768));
            stage_gemm_h(hb);             // acc += h-partials (x already in)

            // ---- PREFETCH x/seq(t+1): licensed by last poll; loads will land
            // during the exchange-store drain below.
            if (xact) issue(xsrc, l == 1);

            // ---- K-partials -> gred (bufX alias)
            {
                int r0 = g * 4;
                #pragma unroll
                for (int ct = 0; ct < 4; ct++) {
                    *(f32x4*)&gred[w][0][ct][n][r0] = acc0[ct];
                    *(f32x4*)&gred[w][1][ct][n][r0] = acc1[ct];
                }
            }
            __syncthreads();                                  // S3
            float g8[8];
            #pragma unroll
            for (int j = 0; j < 8; j++) {
                g8[j] = (gred[0][uh][w][8*q+j][urow] + gred[1][uh][w][8*q+j][urow])
                      + (gred[2][uh][w][8*q+j][urow] + gred[3][uh][w][8*q+j][urow]);
            }
            float gi0 = g8[0] + bs0[0], gf0 = g8[1] + bs0[1];
            float gg0 = g8[2] + bs0[2], go0 = g8[3] + bs0[3];
            float gi1 = g8[4] + bs1[0], gf1 = g8[5] + bs1[1];
            float gg1 = g8[6] + bs1[2], go1 = g8[7] + bs1[3];

            float c0n = sigmoidf_fast(gf0) * creg.x + sigmoidf_fast(gi0) * tanhf_fast(gg0);
            float c1n = sigmoidf_fast(gf1) * creg.y + sigmoidf_fast(gi1) * tanhf_fast(gg1);
            float h0v = sigmoidf_fast(go0) * tanhf_fast(c0n);
            float h1v = sigmoidf_fast(go1) * tanhf_fast(c1n);
            creg.x = c0n; creg.y = c1n;
            hlast.x = h0v; hlast.y = h1v;

            // ---- direct per-thread exchange store + parallel drain
            unsigned hp = (unsigned)f2bf(h0v) | ((unsigned)f2bf(h1v) << 16);
            {
                char* dp = (l == 0)
                    ? (char*)(seqT  + (size_t)t * 32768)       + exOff
                    : (char*)(hparT + (size_t)(t & 1) * 32768) + exOff;
                asm volatile("global_store_dword %0, %1, off sc0 sc1"
                             :: "v"(dp), "v"(hp) : "memory");
                if (l == 1) {
                    float2 hv2 = {h0v, h1v};
                    *(float2*)((char*)outT + (size_t)t * 131072 + outOff) = hv2;
                }
                asm volatile("s_waitcnt vmcnt(0)" ::: "memory");
            }
            __syncthreads();                                  // S4: all drained
            if (tid == 0)
                __hip_atomic_store(flags + l * 64 + bidl, (unsigned)(s + 1),
                                   __ATOMIC_RELAXED, __HIP_MEMORY_SCOPE_AGENT);
        } else {
            if (tid == 0)
                __hip_atomic_store(flags + l * 64 + bidl, (unsigned)(s + 1),
                                   __ATOMIC_RELAXED, __HIP_MEMORY_SCOPE_AGENT);
            if (xact) issue(xsrc, l == 1);             // l1 s=1: seq(0)
        }

        // ---- tail: land prefetched tile into bufX (counted groups; no-ops
        // when loads already drained by the act's vmcnt(0)), x-gemm for t+1
        if (xact) {
            #pragma unroll
            for (int ct = 0; ct < 4; ct++) {
                acc0[ct] = (f32x4){0.f, 0.f, 0.f, 0.f};
                acc1[ct] = (f32x4){0.f, 0.f, 0.f, 0.f};
            }
            const char* pA0 = bX + rOffA0;
            const char* pA1 = bX + rOffA1;
            const char* pB0 = pA0 + 16 * 2048;
            const char* pB1 = pA1 + 16 * 2048;
#define TGRP(G4, VM) \
            asm volatile("s_waitcnt vmcnt(" VM ")" ::: "memory"); \
            _Pragma("unroll") \
            for (int si = 4*(G4); si < 4*(G4)+4; si++) \
                *(u32x4*)(bX + sbRow + ((ldsCol + si*32) ^ swz)) = hv[si]; \
            { \
                bf16x8 a0 = *(const bf16x8*)(pA0 + (G4)*128); \
                bf16x8 a1 = *(const bf16x8*)(pB0 + (G4)*128); \
                _Pragma("unroll") \
                for (int ct = 0; ct < 4; ct++) { \
                    acc0[ct] = __builtin_amdgcn_mfma_f32_16x16x32_bf16(a0, wx[ct*8+2*(G4)],   acc0[ct],0,0,0); \
                    acc1[ct] = __builtin_amdgcn_mfma_f32_16x16x32_bf16(a1, wx[ct*8+2*(G4)],   acc1[ct],0,0,0); \
                } \
                bf16x8 b0 = *(const bf16x8*)(pA1 + (G4)*128); \
                bf16x8 b1 = *(const bf16x8*)(pB1 + (G4)*128); \
                _Pragma("unroll") \
                for (int ct = 0; ct < 4; ct++) { \
                    acc0[ct] = __builtin_amdgcn_mfma_f32_16x16x32_bf16(b0, wx[ct*8+2*(G4)+1], acc0[ct],0,0,0); \
                    acc1[ct] = __builtin_amdgcn_mfma_f32_16x16x32_bf16(b1, wx[ct*8+2*(G4)+1], acc1[ct],0,0,0); \
                } \
            }
            TGRP(0, "12") TGRP(1, "8") TGRP(2, "4") TGRP(3, "0")
#undef TGRP
        }

        // ---- strict global lockstep: all 128 flags >= s+1
        if (tid < 128) pollge(flags + tid, (unsigned)(s + 1));
        __syncthreads();                                      // S5
    }

    // ---- final states
    float* hF = out + (size_t)8192 * 1024 + (size_t)l * 32768;
    float* cF = out + (size_t)8192 * 1024 + 65536 + (size_t)l * 32768;
    float2 hf2 = {hlast.x, hlast.y};
    *(float2*)&hF[eb * 1024 + em] = hf2;
    float2 cf2 = {creg.x, creg.y};
    *(float2*)&cF[eb * 1024 + em] = cf2;
}

extern "C" void kernel_launch(void* const* d_in, const int* in_sizes, int n_in,
                              void* d_out, int out_size, void* d_ws, size_t ws_size,
                              hipStream_t stream)
{
    const float* x   = (const float*)d_in[0];
    const float* h0  = (const float*)d_in[1];
    const float* c0  = (const float*)d_in[2];
    const float* Wih = (const float*)d_in[3];
    const float* Whh = (const float*)d_in[4];
    const float* bih = (const float*)d_in[5];
    const float* bhh = (const float*)d_in[6];
    float* out = (float*)d_out;

    char* p = (char*)d_ws;
    unsigned short* xT    = (unsigned short*)p; p += (size_t)256 * 32768 * 2;      // 16 MB
    unsigned short* seqT  = (unsigned short*)p; p += (size_t)256 * 32768 * 2;      // 16 MB
    unsigned short* Wcat  = (unsigned short*)p; p += (size_t)2 * 4096 * 2048 * 2;  // 32 MB
    unsigned short* h0T   = (unsigned short*)p; p += (size_t)2 * 32768 * 2;        // 128 KB
    unsigned short* hparT = (unsigned short*)p; p += (size_t)2 * 32768 * 2;        // 128 KB
    float*          outT  = (float*)p;          p += (size_t)256 * 32768 * 4;      // 32 MB
    unsigned int*   flags = (unsigned int*)p;   p += 4096;

    hipMemsetAsync(flags, 0, 4096, stream);
    cvt_w_concat<<<1024, 256, 0, stream>>>(Wih, Wcat, 0,    2 * 4096 * 256);
    cvt_w_concat<<<1024, 256, 0, stream>>>(Whh, Wcat, 1024, 2 * 4096 * 256);
    cvt_x_tiles<<<256, 256, 0, stream>>>(x, xT);
    cvt_h0_tiles<<<2, 256, 0, stream>>>(h0, h0T);

    lstm_fused<<<128, 256, 0, stream>>>(Wcat, xT, seqT, h0T, hparT, outT,
                                        c0, bih, bhh, out, flags);

    out_transpose<<<256, 256, 0, stream>>>(outT, out);
}